// Round 1
// baseline (557.829 us; speedup 1.0000x reference)
//
#include <hip/hip_runtime.h>
#include <math.h>

// Problem constants
#define B_ 32
#define T_ 4096
#define QD_ 1024
#define MD_ 512
#define AD_ 128
#define F_ 32
#define K_ 31
#define PAD_ 15

#define TT 32                 // timesteps per score block (1 wave per block)
#define NBLK (T_ / TT)        // 128 t-blocks per batch

typedef float f32x16 __attribute__((ext_vector_type(16)));
typedef unsigned int uint4v __attribute__((ext_vector_type(4)));

// round-half-up float->bf16 pair packed in one VGPR via v_perm (same as prior kernel)
__device__ inline unsigned pk_bf2(float lo, float hi) {
    unsigned ul = __float_as_uint(lo) + 0x8000u;
    unsigned uh = __float_as_uint(hi) + 0x8000u;
    return __builtin_amdgcn_perm(uh, ul, 0x07060302u);
}

__device__ inline unsigned short f2bf_rn(float f) {
    unsigned u = __float_as_uint(f);
    u += 0x7fffu + ((u >> 16) & 1u);
    return (unsigned short)(u >> 16);
}

__device__ inline float bf2f(unsigned short u) {
    return __uint_as_float(((unsigned)u) << 16);
}

// v_mfma via inline asm. s_nop 1 covers VALU-write -> MFMA-read hazard.
__device__ inline void mfma32(f32x16& c, uint4v a, uint4v b) {
    asm("s_nop 1\n\tv_mfma_f32_32x32x16_bf16 %0, %1, %2, %0"
        : "+v"(c) : "v"(a), "v"(b));
}

// ---------------- K0: swizzle Wm -> bf16 MFMA-fragment order ----------------
// wmT_sw[((kk*4 + ct)*64 + lane)*8 + j] = bf16(Wm[kk*16 + (lane>>5)*8 + j][ct*32 + (lane&31)])
__global__ __launch_bounds__(256) void k_prep(const float* __restrict__ Wm,
                                              unsigned short* __restrict__ wmT_sw) {
    int gid = blockIdx.x * 256 + threadIdx.x;   // 0..8191
    int kk = gid >> 8;
    int ct = (gid >> 6) & 3;
    int lane = gid & 63;
    int k0 = kk * 16 + (lane >> 5) * 8;
    int a = ct * 32 + (lane & 31);
    unsigned short o[8];
#pragma unroll
    for (int j = 0; j < 8; j++) o[j] = f2bf_rn(Wm[(k0 + j) * AD_ + a]);
    uint4v v;
    v[0] = ((unsigned)o[1] << 16) | o[0];
    v[1] = ((unsigned)o[3] << 16) | o[2];
    v[2] = ((unsigned)o[5] << 16) | o[4];
    v[3] = ((unsigned)o[7] << 16) | o[6];
    *(uint4v*)(wmT_sw + (long)gid * 8) = v;
}

// ---------------- K1: processed query ----------------
__global__ __launch_bounds__(128) void k_pq(const float* __restrict__ query,
                                            const float* __restrict__ Wq,
                                            float* __restrict__ pq) {
    int b = blockIdx.x;
    int qc = blockIdx.y;
    int a = threadIdx.x;
    const float* qrow = query + b * QD_ + qc * 128;
    const float* wq = Wq + (qc * 128) * AD_ + a;
    float acc = 0.f;
#pragma unroll 4
    for (int i = 0; i < 128; i++) acc += qrow[i] * wq[i * AD_];
    atomicAdd(&pq[b * AD_ + a], acc);
}

// ---------------- K2: conv + loc@Wl + all biases -> ploc (bf16) -------------
// ploc[b][t][a] = bf16_rn( pq[b][a] + bq[a] + bm[a] + bl[a] + sum_f loc[b][t][f]*Wl[f][a] )
// Identical arithmetic to the previous kernel's s_base (incl. f32 accumulation
// order and single final rounding), so absmax is unchanged.
__global__ __launch_bounds__(256) void k_ploc(
    const float* __restrict__ alignments, const float* __restrict__ convw,
    const float* __restrict__ convb, const float* __restrict__ Wl,
    const float* __restrict__ bl, const float* __restrict__ bm,
    const float* __restrict__ bq, const float* __restrict__ pq,
    unsigned short* __restrict__ ploc) {
    __shared__ float s_cw[F_ * 2 * K_];          // 1984 floats
    __shared__ float s_al[(128 + K_ - 1) * 2];   // 316 floats
    __shared__ float s_loc[128 * F_];            // 4096 floats

    const int tid = threadIdx.x;
    const int b = blockIdx.y;
    const int t0 = blockIdx.x * 128;

    for (int i = tid; i < F_ * 2 * K_; i += 256) s_cw[i] = convw[i];
    for (int i = tid; i < (128 + K_ - 1) * 2; i += 256) {
        int tg = t0 + (i >> 1) - PAD_;
        s_al[i] = (tg >= 0 && tg < T_) ? alignments[((long)b * T_ + tg) * 2 + (i & 1)] : 0.f;
    }
    __syncthreads();

    // location conv: 128 t x 32 f
    for (int i = tid; i < 128 * F_; i += 256) {
        int f = i & (F_ - 1);
        int t = i >> 5;
        float acc = convb[f];
        const float* w0 = &s_cw[f * (2 * K_)];
        const float* w1 = w0 + K_;
        const float2* ap = (const float2*)&s_al[t * 2];
#pragma unroll
        for (int k = 0; k < K_; k++) {
            float2 a2 = ap[k];
            acc += a2.x * w0[k] + a2.y * w1[k];
        }
        s_loc[t * F_ + f] = acc;
    }
    __syncthreads();

    // project to AD with Wl column hoisted into registers
    const int a = tid & 127;
    float wl[F_];
#pragma unroll
    for (int f = 0; f < F_; f++) wl[f] = Wl[f * AD_ + a];
    const float base = pq[b * AD_ + a] + bq[a] + bm[a] + bl[a];
    unsigned short* outp = ploc + ((long)b * T_ + t0) * AD_ + a;
    for (int t = (tid >> 7); t < 128; t += 2) {
        float acc = base;
        const float* lr = &s_loc[t * F_];
#pragma unroll
        for (int f = 0; f < F_; f++) acc += lr[f] * wl[f];
        outp[(long)t * AD_] = f2bf_rn(acc);
    }
}

// ---------------- K3: barrier-free 1-wave MFMA score + partial context ------
// One wave per block: M=32 rows (t), N=128 cols (a), K=512 in 16 chunks of 32.
// A-fragments loaded straight from global (lines fully consumed per chunk),
// packed to bf16 in registers; B (swizzled Wm) is L2-resident. No LDS staging,
// no __syncthreads -> fully independent waves, HBM-latency hidden by TLP.
__global__ __launch_bounds__(64) void k_score_ctx(
    const float* __restrict__ memory, const unsigned char* __restrict__ mask,
    const unsigned short* __restrict__ wmT_sw, const unsigned short* __restrict__ ploc,
    const float* __restrict__ vw, const float* __restrict__ vb,
    float* __restrict__ bmax, float* __restrict__ bden,
    float* __restrict__ num, float* __restrict__ oalign) {
    __shared__ __align__(16) float s_sc[TT];
    __shared__ __align__(16) float s_w[TT];

    const int lane = threadIdx.x;
    const int l31 = lane & 31;
    const int h = lane >> 5;
    const int b = blockIdx.y;
    const int blk = blockIdx.x;
    const int t0 = blk * TT;

    const float* aptr = memory + ((long)b * T_ + t0) * MD_;
    const float* arow = aptr + l31 * MD_ + h * 8;     // this lane's fragment source
    const unsigned short* bpk = wmT_sw + lane * 8;

    f32x16 c0, c1, c2, c3;
#pragma unroll
    for (int i = 0; i < 16; i++) { c0[i] = 0.f; c1[i] = 0.f; c2[i] = 0.f; c3[i] = 0.f; }

    for (int cc = 0; cc < 16; ++cc) {
        // A fragments: row = l31, k = cc*32 + h*8 + j (af0), +16 (af1)
        const float4 p0 = *(const float4*)(arow + cc * 32);
        const float4 p1 = *(const float4*)(arow + cc * 32 + 4);
        const float4 p2 = *(const float4*)(arow + cc * 32 + 16);
        const float4 p3 = *(const float4*)(arow + cc * 32 + 20);
        const int kb0 = (2 * cc) * 2048;     // ushort offset of kk=2cc block
        const int kb1 = kb0 + 2048;
        uint4v b00 = *(const uint4v*)(bpk + kb0);
        uint4v b01 = *(const uint4v*)(bpk + kb0 + 512);
        uint4v b02 = *(const uint4v*)(bpk + kb0 + 1024);
        uint4v b03 = *(const uint4v*)(bpk + kb0 + 1536);
        uint4v b10 = *(const uint4v*)(bpk + kb1);
        uint4v b11 = *(const uint4v*)(bpk + kb1 + 512);
        uint4v b12 = *(const uint4v*)(bpk + kb1 + 1024);
        uint4v b13 = *(const uint4v*)(bpk + kb1 + 1536);
        uint4v af0, af1;
        af0[0] = pk_bf2(p0.x, p0.y); af0[1] = pk_bf2(p0.z, p0.w);
        af0[2] = pk_bf2(p1.x, p1.y); af0[3] = pk_bf2(p1.z, p1.w);
        af1[0] = pk_bf2(p2.x, p2.y); af1[1] = pk_bf2(p2.z, p2.w);
        af1[2] = pk_bf2(p3.x, p3.y); af1[3] = pk_bf2(p3.z, p3.w);
        mfma32(c0, af0, b00); mfma32(c1, af0, b01);
        mfma32(c2, af0, b02); mfma32(c3, af0, b03);
        mfma32(c0, af1, b10); mfma32(c1, af1, b11);
        mfma32(c2, af1, b12); mfma32(c3, af1, b13);
    }
    // drain MFMA->VALU hazard
    asm volatile("s_nop 7\n\ts_nop 7\n\ts_nop 7" ::: "memory");

    // --- epilogue: tanh, dot with v, reduce over a (in-register + wave LDS) ---
    const unsigned short* plp = ploc + ((long)b * T_ + t0) * AD_ + l31;
    const float vw0 = vw[l31];
    const float vw1 = vw[32 + l31];
    const float vw2 = vw[64 + l31];
    const float vw3 = vw[96 + l31];
#pragma unroll
    for (int i = 0; i < 16; i++) {
        const int row = (i & 3) + 8 * (i >> 2) + 4 * h;
        const unsigned short* pr = plp + row * AD_;
        float s = tanhf(c0[i] + bf2f(pr[0]))  * vw0
                + tanhf(c1[i] + bf2f(pr[32])) * vw1
                + tanhf(c2[i] + bf2f(pr[64])) * vw2
                + tanhf(c3[i] + bf2f(pr[96])) * vw3;
        s += __shfl_xor(s, 1);
        s += __shfl_xor(s, 2);
        s += __shfl_xor(s, 4);
        s += __shfl_xor(s, 8);
        s += __shfl_xor(s, 16);
        if (l31 == 0) s_sc[row] = s;   // two halves cover disjoint rows
    }

    // add v_b, apply mask (lanes 0..31 own one row each)
    if (lane < TT) {
        float s = s_sc[lane] + vb[0];
        if (mask[(long)b * T_ + t0 + lane]) s = -INFINITY;
        s_sc[lane] = s;
    }
    // local softmax stats
    float m = -INFINITY;
#pragma unroll
    for (int r = 0; r < TT; r++) m = fmaxf(m, s_sc[r]);
    float e = 0.f;
    if (lane < TT) {
        e = (m == -INFINITY) ? 0.f : expf(s_sc[lane] - m);
        s_w[lane] = e;
        oalign[(long)b * T_ + t0 + lane] = e;   // rescaled in k_reduce
    }
    float d = e;
    d += __shfl_xor(d, 1);
    d += __shfl_xor(d, 2);
    d += __shfl_xor(d, 4);
    d += __shfl_xor(d, 8);
    d += __shfl_xor(d, 16);
    if (lane == 0) { bmax[b * NBLK + blk] = m; bden[b * NBLK + blk] = d; }

    // --- partial context: num[md] = sum_t e_t * mem[t][md] (tile L2-hot) ---
    const float2* mp = (const float2*)aptr + lane;
    float2 a0 = make_float2(0.f, 0.f), a1 = make_float2(0.f, 0.f);
    float2 a2 = make_float2(0.f, 0.f), a3 = make_float2(0.f, 0.f);
#pragma unroll 8
    for (int t = 0; t < TT; t++) {
        const float wt = s_w[t];
        const float2 v0 = mp[t * 256];
        const float2 v1 = mp[t * 256 + 64];
        const float2 v2 = mp[t * 256 + 128];
        const float2 v3 = mp[t * 256 + 192];
        a0.x += wt * v0.x; a0.y += wt * v0.y;
        a1.x += wt * v1.x; a1.y += wt * v1.y;
        a2.x += wt * v2.x; a2.y += wt * v2.y;
        a3.x += wt * v3.x; a3.y += wt * v3.y;
    }
    float2* np = (float2*)(num + ((long)b * NBLK + blk) * MD_) + lane;
    np[0] = a0; np[64] = a1; np[128] = a2; np[192] = a3;
}

// ---------------- K4: combine partials -> ctx + rescale oalign --------------
__global__ __launch_bounds__(512) void k_reduce(
    const float* __restrict__ bmax, const float* __restrict__ bden,
    const float* __restrict__ num,
    float* __restrict__ ctx, float* __restrict__ oalign) {
    int b = blockIdx.x;
    int tid = threadIdx.x;
    __shared__ float sm[NBLK], sf[NBLK];
    __shared__ float sD;
    if (tid < NBLK) sm[tid] = bmax[b * NBLK + tid];
    __syncthreads();
    float M = -INFINITY;
#pragma unroll 8
    for (int i = 0; i < NBLK; i++) M = fmaxf(M, sm[i]);
    if (tid < NBLK) sf[tid] = expf(sm[tid] - M);
    __syncthreads();
    if (tid == 0) {
        float D = 0.f;
        for (int i = 0; i < NBLK; i++) D += sf[i] * bden[b * NBLK + i];
        sD = D;
    }
    __syncthreads();
    const float invD = 1.f / sD;

    // ctx
    float acc = 0.f;
    const float* np = num + (long)b * NBLK * MD_ + tid;
#pragma unroll 8
    for (int blk = 0; blk < NBLK; blk++) acc += sf[blk] * np[blk * MD_];
    ctx[b * MD_ + tid] = acc * invD;

    // alignments: oalign currently holds exp(s - m_blk); rescale to softmax
    for (int t = tid; t < T_; t += 512) {
        oalign[(long)b * T_ + t] *= sf[t >> 5] * invD;
    }
}

extern "C" void kernel_launch(void* const* d_in, const int* in_sizes, int n_in,
                              void* d_out, int out_size, void* d_ws, size_t ws_size,
                              hipStream_t stream) {
    const float* query      = (const float*)d_in[0];
    const float* memory     = (const float*)d_in[1];
    const float* alignments = (const float*)d_in[2];
    const unsigned char* mask = (const unsigned char*)d_in[3];
    const float* Wq    = (const float*)d_in[4];
    const float* bq    = (const float*)d_in[5];
    const float* Wm    = (const float*)d_in[6];
    const float* bm    = (const float*)d_in[7];
    const float* convw = (const float*)d_in[8];
    const float* convb = (const float*)d_in[9];
    const float* Wl    = (const float*)d_in[10];
    const float* bl    = (const float*)d_in[11];
    const float* vw    = (const float*)d_in[12];
    const float* vb    = (const float*)d_in[13];

    float* out = (float*)d_out;
    float* ctx = out;                      // [B,MD]
    float* oalign = out + B_ * MD_;        // [B,T]

    // workspace layout (requires ~42.2 MB):
    //   pq     : B*AD floats              (16 KB)
    //   bmax   : B*NBLK floats            (16 KB)
    //   bden   : B*NBLK floats            (16 KB)
    //   num    : B*NBLK*MD floats         (8 MB)
    //   wmT_sw : 65536 ushorts            (128 KB)
    //   ploc   : B*T*AD ushorts           (32 MB)
    float* ws = (float*)d_ws;
    float* pq     = ws;
    float* bmax   = pq + B_ * AD_;
    float* bden   = bmax + B_ * NBLK;
    float* num    = bden + B_ * NBLK;
    unsigned short* wmT_sw = (unsigned short*)(num + (long)B_ * NBLK * MD_);
    unsigned short* ploc   = wmT_sw + (long)8192 * 8;

    hipMemsetAsync(pq, 0, B_ * AD_ * sizeof(float), stream);

    k_prep<<<32, 256, 0, stream>>>(Wm, wmT_sw);
    k_pq<<<dim3(B_, QD_ / 128), 128, 0, stream>>>(query, Wq, pq);
    k_ploc<<<dim3(T_ / 128, B_), 256, 0, stream>>>(alignments, convw, convb, Wl, bl, bm, bq, pq, ploc);
    k_score_ctx<<<dim3(NBLK, B_), 64, 0, stream>>>(
        memory, mask, wmT_sw, ploc, vw, vb, bmax, bden, num, oalign);
    k_reduce<<<B_, 512, 0, stream>>>(bmax, bden, num, ctx, oalign);
}